// Round 9
// baseline (175.312 us; speedup 1.0000x reference)
//
#include <hip/hip_runtime.h>
#include <stdint.h>

#define S_LEN 3072
#define DIM   1536
#define NH    12
#define HD    128
#define QKV_N 4608   // 3*DIM

typedef unsigned short u16;
typedef __bf16 bf16x8 __attribute__((ext_vector_type(8)));
typedef float  f32x4  __attribute__((ext_vector_type(4)));
typedef u16    u16x8  __attribute__((ext_vector_type(8)));
typedef u16    u16x4  __attribute__((ext_vector_type(4)));

#define AS1 __attribute__((address_space(1)))
#define AS3 __attribute__((address_space(3)))
#define GLL16(g, l) __builtin_amdgcn_global_load_lds((AS1 void*)(g), (AS3 void*)(l), 16, 0, 0)

__device__ __forceinline__ u16 f2bf(float f) {
  unsigned u = __float_as_uint(f);
  u = (u + 0x7fffu + ((u >> 16) & 1u)) >> 16;   // RNE
  return (u16)u;
}
__device__ __forceinline__ float bf2f(u16 b) {
  return __uint_as_float(((unsigned)b) << 16);
}

// ---------------- fused fp32 -> bf16 convert (3 tensors, one launch) ----------
__global__ __launch_bounds__(256) void cvt_bf16_3(const float* __restrict__ in0, u16* __restrict__ out0, int n0,
                                                  const float* __restrict__ in1, u16* __restrict__ out1, int n1,
                                                  const float* __restrict__ in2, u16* __restrict__ out2, int n2) {
  int total = n0 + n1 + n2;
  int stride = gridDim.x * blockDim.x;
  for (int i = blockIdx.x * blockDim.x + threadIdx.x; i < total; i += stride) {
    const float* src; u16* dst; int j;
    if (i < n0)           { src = in0; dst = out0; j = i; }
    else if (i < n0 + n1) { src = in1; dst = out1; j = i - n0; }
    else                  { src = in2; dst = out2; j = i - n0 - n1; }
    float4 v = ((const float4*)src)[j];
    ushort4 o;
    o.x = f2bf(v.x); o.y = f2bf(v.y); o.z = f2bf(v.z); o.w = f2bf(v.w);
    ((ushort4*)dst)[j] = o;
  }
}

// ============ GEMM1 (QKV): 128x256 tile, 4 waves, A-only LDS, B from global ====
// LDS traffic cut ~33% vs 256^2-both-staged (GEMM1 is LDS-read-bound: A re-read
// by 4 waves was 128KB + B 64KB per K-tile). B-frags: 16 rows x 64B coalesced
// global loads, L2-resident, prefetched one section early (compiler-waited).
// A regions: [buf][ks] of 128x32 bf16 (8KB); slot = lq ^ (row&3) -> 2-way free.
// vmcnt ledger: sec0-end vmcnt(4) forces kt.ks1-A; sec1-end vmcnt(6) forces
// kt+1.ks0-A (B loads are older than the stage they'd mask; compiler use-waits
// on B force all older loads).
__global__ __launch_bounds__(256, 2) void gemm_qkv(const u16* __restrict__ A,
                                                   const u16* __restrict__ B,
                                                   const float* __restrict__ bias,
                                                   u16* __restrict__ Cout,
                                                   int M, int N, int K) {
  __shared__ __attribute__((aligned(16))) u16 lds[32768];  // 64 KiB (loop: 32KB)

  const int t = threadIdx.x;
  const int l = t & 63;
  const int w = t >> 6;        // 0..3 = N 64-col slice
  const int lr = l & 15;
  const int lq = l >> 4;

  const int nbx = N >> 8;      // 18
  const int nwg = gridDim.x;   // 432 (divisible by 8)
  const int q = nwg >> 3, r = nwg & 7;
  const int xcd = blockIdx.x & 7, rest = blockIdx.x >> 3;
  const int wgid = (xcd < r ? xcd * (q + 1) : r * (q + 1) + (xcd - r) * q) + rest;
  const int m0 = (wgid / nbx) * 128;
  const int n0 = (wgid % nbx) * 256;
  const int nk = K >> 6;

  f32x4 acc[8][4];
  #pragma unroll
  for (int i = 0; i < 8; ++i)
    #pragma unroll
    for (int j = 0; j < 4; ++j) acc[i][j] = f32x4{0.f, 0.f, 0.f, 0.f};

  // stage A half-tile (128x32) for K-slice ks of tile kt into [buf][ks]
  auto stageA = [&](int buf, int ks, int kt) {
    u16* dst = lds + ((buf << 1) | ks) * 4096;
    #pragma unroll
    for (int i = 0; i < 2; ++i) {
      int C = t + i * 256;            // 512 chunks of 16B
      int row = C >> 2, slot = C & 3;
      int ch = slot ^ (row & 3);      // pre-swizzled source, linear LDS dest
      GLL16(A + (size_t)(m0 + row) * K + kt * 64 + ks * 32 + ch * 8, dst + C * 8);
    }
  };
  auto loadB = [&](bf16x8* bf, int kt, int ks) {
    #pragma unroll
    for (int ni = 0; ni < 4; ++ni)
      bf[ni] = *(const bf16x8*)(B + (size_t)(n0 + w * 64 + ni * 16 + lr) * K +
                                kt * 64 + ks * 32 + lq * 8);
  };
  auto readA = [&](bf16x8* af, int buf, int ks) {
    const u16* reg = lds + ((buf << 1) | ks) * 4096;
    #pragma unroll
    for (int mi = 0; mi < 8; ++mi) {
      int row = mi * 16 + lr;
      int slot = lq ^ (row & 3);
      af[mi] = *(const bf16x8*)(reg + row * 32 + slot * 8);
    }
  };

  bf16x8 bA[4], bB[4];
  // prologue: tile0 A both halves + B(ks0); vmcnt(6) -> t0.ks0-A landed
  stageA(0, 0, 0);
  stageA(0, 1, 0);
  loadB(bA, 0, 0);
  asm volatile("s_waitcnt vmcnt(6)" ::: "memory");
  __builtin_amdgcn_s_barrier();

  for (int kt = 0; kt < nk; ++kt) {
    const int buf = kt & 1, nbuf = buf ^ 1;
    const bool st = (kt + 1 < nk);

    // ---- section ks0 ----
    loadB(bB, kt, 1);
    if (st) stageA(nbuf, 0, kt + 1);
    {
      bf16x8 af[8];
      readA(af, buf, 0);
      __builtin_amdgcn_s_setprio(1);
      #pragma unroll
      for (int mi = 0; mi < 8; ++mi)
        #pragma unroll
        for (int ni = 0; ni < 4; ++ni)
          acc[mi][ni] = __builtin_amdgcn_mfma_f32_16x16x32_bf16(af[mi], bA[ni],
                                                                acc[mi][ni], 0, 0, 0);
      __builtin_amdgcn_s_setprio(0);
    }
    asm volatile("s_waitcnt vmcnt(4)" ::: "memory");   // forces kt.ks1-A landed
    __builtin_amdgcn_s_barrier();

    // ---- section ks1 ----
    if (st) { loadB(bA, kt + 1, 0); stageA(nbuf, 1, kt + 1); }
    {
      bf16x8 af[8];
      readA(af, buf, 1);
      __builtin_amdgcn_s_setprio(1);
      #pragma unroll
      for (int mi = 0; mi < 8; ++mi)
        #pragma unroll
        for (int ni = 0; ni < 4; ++ni)
          acc[mi][ni] = __builtin_amdgcn_mfma_f32_16x16x32_bf16(af[mi], bB[ni],
                                                                acc[mi][ni], 0, 0, 0);
      __builtin_amdgcn_s_setprio(0);
    }
    asm volatile("s_waitcnt vmcnt(6)" ::: "memory");   // forces kt+1.ks0-A landed
    __builtin_amdgcn_s_barrier();
  }

  // ---- epilogue: stage 128x256 C in LDS (64KB), store coalesced + bias ----
  {
    float bv[4];
    #pragma unroll
    for (int ni = 0; ni < 4; ++ni)
      bv[ni] = bias ? bias[n0 + w * 64 + ni * 16 + lr] : 0.f;
    #pragma unroll
    for (int mi = 0; mi < 8; ++mi) {
      int row = mi * 16 + lq * 4;
      #pragma unroll
      for (int ni = 0; ni < 4; ++ni) {
        int scol = (w * 64 + ni * 16 + lr) ^ (lq << 4);
        #pragma unroll
        for (int rr = 0; rr < 4; ++rr)
          lds[(row + rr) * 256 + scol] = f2bf(acc[mi][ni][rr] + bv[ni]);
      }
    }
    __syncthreads();
    #pragma unroll
    for (int i = 0; i < 16; ++i) {
      int id = i * 256 + t;
      int row = id >> 5, c16 = id & 31;
      int s = (row >> 2) & 3;
      u16x8 v = *(const u16x8*)(lds + row * 256 + ((c16 * 8) ^ (s << 4)));
      *(u16x8*)(Cout + (size_t)(m0 + row) * N + n0 + c16 * 8) = v;
    }
  }
}

// ---------------- GEMM: C[M][N] = A[M][K] * B[N][K]^T (128x128, for GEMM2) ------
__device__ __forceinline__ bf16x8 lds_frag(const u16* base, int row, int ch) {
  return *(const bf16x8*)(base + row * 64 + ((ch ^ row) & 7) * 8);
}

template <bool BIAS, bool OUTF32>
__global__ __launch_bounds__(256) void gemm_bt(const u16* __restrict__ A,
                                               const u16* __restrict__ B,
                                               const float* __restrict__ bias,
                                               void* __restrict__ Cout,
                                               int M, int N, int K) {
  __shared__ u16 Asm[128 * 64];
  __shared__ u16 Bsm[128 * 64];
  const int t = threadIdx.x;
  const int l = t & 63;
  const int w = t >> 6;
  const int wm = w >> 1, wn = w & 1;
  const int m0 = blockIdx.y * 128, n0 = blockIdx.x * 128;

  f32x4 acc[4][4];
  #pragma unroll
  for (int i = 0; i < 4; ++i)
    #pragma unroll
    for (int j = 0; j < 4; ++j) acc[i][j] = f32x4{0.f, 0.f, 0.f, 0.f};

  for (int k0 = 0; k0 < K; k0 += 64) {
    __syncthreads();
    #pragma unroll
    for (int r4 = 0; r4 < 4; ++r4) {
      int C = t + r4 * 256;
      int row = C >> 3, ch = C & 7;
      int sch = (ch ^ row) & 7;
      GLL16(A + (size_t)(m0 + row) * K + k0 + sch * 8, Asm + (size_t)C * 8);
      GLL16(B + (size_t)(n0 + row) * K + k0 + sch * 8, Bsm + (size_t)C * 8);
    }
    __syncthreads();
    #pragma unroll
    for (int ks = 0; ks < 2; ++ks) {
      bf16x8 af[4], bfr[4];
      #pragma unroll
      for (int mi = 0; mi < 4; ++mi)
        af[mi] = lds_frag(Asm, wm * 64 + mi * 16 + (l & 15), ks * 4 + (l >> 4));
      #pragma unroll
      for (int ni = 0; ni < 4; ++ni)
        bfr[ni] = lds_frag(Bsm, wn * 64 + ni * 16 + (l & 15), ks * 4 + (l >> 4));
      #pragma unroll
      for (int mi = 0; mi < 4; ++mi)
        #pragma unroll
        for (int ni = 0; ni < 4; ++ni)
          acc[mi][ni] = __builtin_amdgcn_mfma_f32_16x16x32_bf16(af[mi], bfr[ni],
                                                                acc[mi][ni], 0, 0, 0);
    }
  }

  #pragma unroll
  for (int ni = 0; ni < 4; ++ni) {
    int col = n0 + wn * 64 + ni * 16 + (l & 15);
    float bv = 0.f;
    if (BIAS) bv = bias[col];
    #pragma unroll
    for (int mi = 0; mi < 4; ++mi) {
      int rbase = m0 + wm * 64 + mi * 16 + ((l >> 4) << 2);
      #pragma unroll
      for (int rr = 0; rr < 4; ++rr) {
        float v = acc[mi][ni][rr] + bv;
        if (OUTF32)
          ((float*)Cout)[(size_t)(rbase + rr) * N + col] = v;
        else
          ((u16*)Cout)[(size_t)(rbase + rr) * N + col] = f2bf(v);
      }
    }
  }
}

// ---------------- RoPE + repack q/k, transpose v (vectorized) ----------------
__global__ __launch_bounds__(256) void rope_pack(const u16* __restrict__ QKV,
                                                 const float* __restrict__ cosb,
                                                 const float* __restrict__ sinb,
                                                 u16* __restrict__ Qp,
                                                 u16* __restrict__ Kp,
                                                 u16* __restrict__ Vt) {
  __shared__ u16 vtile[64][128];
  const int t = threadIdx.x;
  const int s0 = blockIdx.x * 64;
  const int h = blockIdx.y;

  const int srow = s0 + (t >> 2);
  const int d0 = (t & 3) * 16;
  const u16* qkvrow = QKV + (size_t)srow * QKV_N + h * HD;
  const float qscale = 0.08838834764831845f * 1.4426950408889634f; // HD^-0.5 * log2(e)

  float cl[16], chh[16], sl[16], shh[16];
  #pragma unroll
  for (int g = 0; g < 4; ++g) {
    *(float4*)(cl + 4 * g)  = *(const float4*)(cosb + srow * HD + d0 + 4 * g);
    *(float4*)(chh + 4 * g) = *(const float4*)(cosb + srow * HD + d0 + 64 + 4 * g);
    *(float4*)(sl + 4 * g)  = *(const float4*)(sinb + srow * HD + d0 + 4 * g);
    *(float4*)(shh + 4 * g) = *(const float4*)(sinb + srow * HD + d0 + 64 + 4 * g);
  }

  #pragma unroll
  for (int which = 0; which < 2; ++which) {
    const u16* src = qkvrow + which * DIM;
    u16* dst = (which ? Kp : Qp) + ((size_t)h * S_LEN + srow) * HD;
    const float sc = which ? 1.f : qscale;
    u16x8 xl0 = *(const u16x8*)(src + d0);
    u16x8 xl1 = *(const u16x8*)(src + d0 + 8);
    u16x8 xh0 = *(const u16x8*)(src + d0 + 64);
    u16x8 xh1 = *(const u16x8*)(src + d0 + 72);
    u16x8 o0, o1, o2, o3;
    #pragma unroll
    for (int j = 0; j < 8; ++j) {
      float xlo = bf2f(xl0[j]), xhi = bf2f(xh0[j]);
      o0[j] = f2bf((xlo * cl[j] - xhi * sl[j]) * sc);
      o2[j] = f2bf((xhi * chh[j] + xlo * shh[j]) * sc);
      float xlo2 = bf2f(xl1[j]), xhi2 = bf2f(xh1[j]);
      o1[j] = f2bf((xlo2 * cl[j + 8] - xhi2 * sl[j + 8]) * sc);
      o3[j] = f2bf((xhi2 * chh[j + 8] + xlo2 * shh[j + 8]) * sc);
    }
    *(u16x8*)(dst + d0)      = o0;
    *(u16x8*)(dst + d0 + 8)  = o1;
    *(u16x8*)(dst + d0 + 64) = o2;
    *(u16x8*)(dst + d0 + 72) = o3;
  }

  #pragma unroll
  for (int r4 = 0; r4 < 4; ++r4) {
    int C = t + r4 * 256;
    int row = C >> 4, ch = C & 15;
    *(uint4*)(&vtile[row][ch * 8]) =
        *(const uint4*)(QKV + (size_t)(s0 + row) * QKV_N + 2 * DIM + h * HD + ch * 8);
  }
  __syncthreads();
  const int d = t >> 1;
  const int sc0 = (t & 1) * 32;
  u16* vdst = Vt + ((size_t)h * HD + d) * S_LEN + s0 + sc0;
  #pragma unroll
  for (int j = 0; j < 32; j += 8) {
    u16x8 v;
    #pragma unroll
    for (int e = 0; e < 8; ++e) v[e] = vtile[sc0 + j + e][d];
    *(u16x8*)(vdst + j) = v;
  }
}

// -------- flash attention (R7 config): QBLK=64, 4 waves, swapped-QK^T softmax ---
__global__ __launch_bounds__(256) void attn_fwd(const u16* __restrict__ Qp,
                                                const u16* __restrict__ Kp,
                                                const u16* __restrict__ Vt,
                                                const int* __restrict__ cu,
                                                u16* __restrict__ Obf) {
  __shared__ u16 K_lds[64 * 128];    // [kv][d], chunk-swizzled
  __shared__ u16 VT_lds[128 * 64];   // [d][kv], chunk-swizzled
  __shared__ u16 P_lds[4][16 * 76];  // per-wave P[q][k], stride 76

  const int t = threadIdx.x;
  const int l = t & 63;
  const int w = t >> 6;
  const int lr = l & 15;
  const int lq = l >> 4;
  const int q0 = blockIdx.x * 64;
  const int h = blockIdx.y;

  int cs = 0, ce = S_LEN;
  #pragma unroll
  for (int b = 0; b < 4; ++b) {
    int lo = cu[b], hi = cu[b + 1];
    if (q0 >= lo && q0 < hi) { cs = lo; ce = hi; }
  }

  const int qrow = q0 + w * 16 + lr;
  bf16x8 qf[4];
  const u16* qptr = Qp + ((size_t)h * S_LEN + qrow) * HD + lq * 8;
  #pragma unroll
  for (int ks = 0; ks < 4; ++ks) qf[ks] = *(const bf16x8*)(qptr + ks * 32);

  f32x4 acc_o[8];
  #pragma unroll
  for (int i = 0; i < 8; ++i) acc_o[i] = f32x4{0.f, 0.f, 0.f, 0.f};
  float m_run = -1e30f, l_run = 0.f;   // per-lane: row q = lr

  for (int kv0 = cs; kv0 < ce; kv0 += 64) {
    __syncthreads();
    {
      const u16* kbase = Kp + ((size_t)h * S_LEN + kv0) * HD;
      #pragma unroll
      for (int r4 = 0; r4 < 4; ++r4) {
        int C = t + r4 * 256;
        int row = C >> 4, ch = C & 15;
        int sch = (ch & 8) | ((ch ^ row) & 7);
        GLL16(kbase + row * HD + sch * 8, K_lds + (size_t)C * 8);
      }
      const u16* vbase = Vt + (size_t)h * HD * S_LEN + kv0;
      #pragma unroll
      for (int r4 = 0; r4 < 4; ++r4) {
        int C = t + r4 * 256;
        int row = C >> 3, ch = C & 7;
        int sch = (ch ^ row) & 7;
        GLL16(vbase + (size_t)row * S_LEN + sch * 8, VT_lds + (size_t)C * 8);
      }
    }
    __syncthreads();

    // S^T = K Q^T : s_acc[nf] reg r holds S[q=lr][k = nf*16 + lq*4 + r]
    f32x4 s_acc[4];
    __builtin_amdgcn_s_setprio(1);
    #pragma unroll
    for (int nf = 0; nf < 4; ++nf) {
      s_acc[nf] = f32x4{0.f, 0.f, 0.f, 0.f};
      int krow = nf * 16 + lr;
      #pragma unroll
      for (int ks = 0; ks < 4; ++ks) {
        int ch = ks * 4 + lq;
        int sch = (ch & 8) | ((ch ^ krow) & 7);
        bf16x8 kf = *(const bf16x8*)(K_lds + krow * 128 + sch * 8);
        s_acc[nf] = __builtin_amdgcn_mfma_f32_16x16x32_bf16(kf, qf[ks], s_acc[nf], 0, 0, 0);
      }
    }
    __builtin_amdgcn_s_setprio(0);

    // in-register row softmax (q = lr), 16 k-values per lane
    float vmax = -1e30f;
    #pragma unroll
    for (int nf = 0; nf < 4; ++nf)
      #pragma unroll
      for (int r = 0; r < 4; ++r) vmax = fmaxf(vmax, s_acc[nf][r]);
    vmax = fmaxf(vmax, __shfl_xor(vmax, 16, 64));
    vmax = fmaxf(vmax, __shfl_xor(vmax, 32, 64));
    float mn = fmaxf(m_run, vmax);
    float alpha = __builtin_amdgcn_exp2f(m_run - mn);
    m_run = mn;
    float pv[4][4], sum = 0.f;
    #pragma unroll
    for (int nf = 0; nf < 4; ++nf)
      #pragma unroll
      for (int r = 0; r < 4; ++r) {
        float e = __builtin_amdgcn_exp2f(s_acc[nf][r] - mn);
        pv[nf][r] = e;
        sum += e;
      }
    sum += __shfl_xor(sum, 16, 64);
    sum += __shfl_xor(sum, 32, 64);
    l_run = l_run * alpha + sum;

    // rescale O: alpha for O-row q = lq*4+r lives at lane lq*16 + lq*4 + r
    float alphaO[4];
    #pragma unroll
    for (int r = 0; r < 4; ++r) alphaO[r] = __shfl(alpha, lq * 20 + r, 64);
    #pragma unroll
    for (int onf = 0; onf < 8; ++onf)
      #pragma unroll
      for (int r = 0; r < 4; ++r) acc_o[onf][r] *= alphaO[r];

    // P -> LDS: lane writes P[q=lr][k = nf*16 + lq*4 .. +3] as one b64
    u16* pl = P_lds[w];
    #pragma unroll
    for (int nf = 0; nf < 4; ++nf) {
      u16x4 pk;
      #pragma unroll
      for (int r = 0; r < 4; ++r) pk[r] = f2bf(pv[nf][r]);
      *(u16x4*)(pl + lr * 76 + nf * 16 + lq * 4) = pk;
    }

    // O += P V
    __builtin_amdgcn_s_setprio(1);
    #pragma unroll
    for (int ks = 0; ks < 2; ++ks) {
      bf16x8 pa = *(const bf16x8*)(pl + lr * 76 + ks * 32 + lq * 8);
      #pragma unroll
      for (int onf = 0; onf < 8; ++onf) {
        int d = onf * 16 + lr;
        int ch = ks * 4 + lq;
        int sch = (ch ^ d) & 7;
        bf16x8 vf = *(const bf16x8*)(VT_lds + d * 64 + sch * 8);
        acc_o[onf] = __builtin_amdgcn_mfma_f32_16x16x32_bf16(pa, vf, acc_o[onf], 0, 0, 0);
      }
    }
    __builtin_amdgcn_s_setprio(0);
  }

  // epilogue: inv for O-row q = lq*4+r fetched from lane lq*20+r
  float invO[4];
  #pragma unroll
  for (int r = 0; r < 4; ++r) invO[r] = 1.f / __shfl(l_run, lq * 20 + r, 64);
  #pragma unroll
  for (int r = 0; r < 4; ++r) {
    int srow = q0 + w * 16 + (lq << 2) + r;
    u16* orow = Obf + (size_t)srow * DIM + h * HD + lr;
    #pragma unroll
    for (int onf = 0; onf < 8; ++onf) orow[onf * 16] = f2bf(acc_o[onf][r] * invO[r]);
  }
}

extern "C" void kernel_launch(void* const* d_in, const int* in_sizes, int n_in,
                              void* d_out, int out_size, void* d_ws, size_t ws_size,
                              hipStream_t stream) {
  const float* hidden = (const float*)d_in[0];
  const float* cosb   = (const float*)d_in[1];
  const float* sinb   = (const float*)d_in[2];
  const float* qkv_w  = (const float*)d_in[3];
  const float* qkv_b  = (const float*)d_in[4];
  const float* proj_w = (const float*)d_in[5];
  const int*   cu     = (const int*)d_in[6];

  u16* Hbf   = (u16*)d_ws;
  u16* Wqkv  = Hbf   + (size_t)S_LEN * DIM;
  u16* Wproj = Wqkv  + (size_t)QKV_N * DIM;
  u16* QKVbf = Wproj + (size_t)DIM * DIM;
  u16* Kp    = QKVbf + (size_t)S_LEN * QKV_N;
  u16* Vt    = Kp    + (size_t)NH * S_LEN * HD;
  u16* Qp    = Wqkv;  // reuse: Wqkv dead after GEMM1
  u16* Abf   = Hbf;   // reuse: Hbf dead after GEMM1

  cvt_bf16_3<<<2048, 256, 0, stream>>>(hidden, Hbf, S_LEN * DIM / 4,
                                       qkv_w, Wqkv, QKV_N * DIM / 4,
                                       proj_w, Wproj, DIM * DIM / 4);

  gemm_qkv<<<(S_LEN / 128) * (QKV_N / 256), 256, 0, stream>>>(
      Hbf, Wqkv, qkv_b, QKVbf, S_LEN, QKV_N, DIM);

  rope_pack<<<dim3(S_LEN / 64, NH), 256, 0, stream>>>(QKVbf, cosb, sinb, Qp, Kp, Vt);

  attn_fwd<<<dim3(S_LEN / 64, NH), 256, 0, stream>>>(Qp, Kp, Vt, cu, Abf);

  gemm_bt<false, true><<<dim3(DIM / 128, S_LEN / 128), 256, 0, stream>>>(
      Abf, Wproj, nullptr, d_out, S_LEN, DIM, DIM);
}

// Round 10
// 150.914 us; speedup vs baseline: 1.1617x; 1.1617x over previous
//
#include <hip/hip_runtime.h>
#include <stdint.h>

#define S_LEN 3072
#define DIM   1536
#define NH    12
#define HD    128
#define QKV_N 4608   // 3*DIM

typedef unsigned short u16;
typedef __bf16 bf16x8 __attribute__((ext_vector_type(8)));
typedef float  f32x4  __attribute__((ext_vector_type(4)));
typedef u16    u16x8  __attribute__((ext_vector_type(8)));
typedef u16    u16x4  __attribute__((ext_vector_type(4)));

#define AS1 __attribute__((address_space(1)))
#define AS3 __attribute__((address_space(3)))
#define GLL16(g, l) __builtin_amdgcn_global_load_lds((AS1 void*)(g), (AS3 void*)(l), 16, 0, 0)

__device__ __forceinline__ u16 f2bf(float f) {
  unsigned u = __float_as_uint(f);
  u = (u + 0x7fffu + ((u >> 16) & 1u)) >> 16;   // RNE
  return (u16)u;
}
__device__ __forceinline__ float bf2f(u16 b) {
  return __uint_as_float(((unsigned)b) << 16);
}

// ---------------- fused fp32 -> bf16 convert (3 tensors, one launch) ----------
__global__ __launch_bounds__(256) void cvt_bf16_3(const float* __restrict__ in0, u16* __restrict__ out0, int n0,
                                                  const float* __restrict__ in1, u16* __restrict__ out1, int n1,
                                                  const float* __restrict__ in2, u16* __restrict__ out2, int n2) {
  int total = n0 + n1 + n2;
  int stride = gridDim.x * blockDim.x;
  for (int i = blockIdx.x * blockDim.x + threadIdx.x; i < total; i += stride) {
    const float* src; u16* dst; int j;
    if (i < n0)           { src = in0; dst = out0; j = i; }
    else if (i < n0 + n1) { src = in1; dst = out1; j = i - n0; }
    else                  { src = in2; dst = out2; j = i - n0 - n1; }
    float4 v = ((const float4*)src)[j];
    ushort4 o;
    o.x = f2bf(v.x); o.y = f2bf(v.y); o.z = f2bf(v.z); o.w = f2bf(v.w);
    ((ushort4*)dst)[j] = o;
  }
}

// ======= GEMM1 (QKV) 256x256 8-phase + FUSED epilogue: rope q/k, transpose v ===
// Main loop identical to the proven R7 gemm_bt_256 (54.5us, 0 conflicts).
// Epilogue: C-tile staged in LDS bf16 with swizzle scol = col ^ (((row>>2)&15)<<4)
// (writer knows (row>>2)&15 = (mi*4+lc)&15). Each tile is wholly q, k or v
// (N=4608, 1536%256==0) and spans exactly 2 heads -> rope partner col^64 is
// tile-local; v is transposed straight out of LDS into Vt[h][d][s].
__global__ __launch_bounds__(512, 2) void gemm_qkvf(const u16* __restrict__ A,
                                                    const u16* __restrict__ B,
                                                    const float* __restrict__ bias,
                                                    const float* __restrict__ cosb,
                                                    const float* __restrict__ sinb,
                                                    u16* __restrict__ Qp,
                                                    u16* __restrict__ Kp,
                                                    u16* __restrict__ Vt,
                                                    int M, int N, int K) {
  __shared__ __attribute__((aligned(16))) u16 lds[8 * 8192];  // 128 KiB

  const int t = threadIdx.x;
  const int l = t & 63;
  const int w = t >> 6;          // 0..7
  const int wm = w >> 2;         // 0..1  (128 rows)
  const int wn = w & 3;          // 0..3  (64 cols)
  const int lr = l & 15;
  const int lc = l >> 4;

  const int nbx = N >> 8;
  const int nwg = gridDim.x;
  const int q = nwg >> 3, r = nwg & 7;
  const int xcd = blockIdx.x & 7, rest = blockIdx.x >> 3;
  const int wgid = (xcd < r ? xcd * (q + 1) : r * (q + 1) + (xcd - r) * q) + rest;
  const int m0 = (wgid / nbx) * 256;
  const int n0 = (wgid % nbx) * 256;

  const int nk = K >> 6;

  f32x4 acc[8][4];
  #pragma unroll
  for (int i = 0; i < 8; ++i)
    #pragma unroll
    for (int j = 0; j < 4; ++j) acc[i][j] = f32x4{0.f, 0.f, 0.f, 0.f};

  auto frag2 = [&](const u16* region, int row, int ch) {
    int L = row >> 1;
    int slot = ((ch + ((row & 1) << 2)) ^ L) & 7;
    return *(const bf16x8*)(region + L * 64 + slot * 8);
  };
  auto stage_half = [&](int buf, int ks, int ab, int kt) {
    const u16* base = ab ? B : A;
    const int x0 = ab ? n0 : m0;
    u16* dst = lds + (((buf << 2) | (ks << 1) | ab) * 8192);
    #pragma unroll
    for (int i = 0; i < 2; ++i) {
      int C = t + i * 512;
      int L = C >> 3, s = C & 7;
      int u = s ^ (L & 7);
      int row = 2 * L + (u >> 2), ch = u & 3;
      const u16* src = base + (size_t)(x0 + row) * K + kt * 64 + ks * 32 + ch * 8;
      GLL16(src, dst + C * 8);
    }
  };

  stage_half(0, 0, 0, 0); stage_half(0, 0, 1, 0);
  stage_half(0, 1, 0, 0); stage_half(0, 1, 1, 0);
  if (nk > 1) { stage_half(1, 0, 0, 1); stage_half(1, 0, 1, 1); }
  asm volatile("s_waitcnt vmcnt(4)" ::: "memory");
  __builtin_amdgcn_s_barrier();

  for (int kt = 0; kt < nk; ++kt) {
    const int buf = kt & 1, nbuf = buf ^ 1;
    const bool st1 = (kt + 1 < nk);
    const bool st2 = (kt + 2 < nk);

    const u16* A0 = lds + (((buf << 2) | 0) * 8192);
    const u16* B0 = lds + (((buf << 2) | 1) * 8192);
    const u16* A1 = lds + (((buf << 2) | 2) * 8192);
    const u16* B1 = lds + (((buf << 2) | 3) * 8192);

    bf16x8 bfrag[4], afr[4];

    // ---- ph0 ----
    #pragma unroll
    for (int ni = 0; ni < 4; ++ni) bfrag[ni] = frag2(B0, wn * 64 + ni * 16 + lr, lc);
    #pragma unroll
    for (int mi = 0; mi < 4; ++mi) afr[mi] = frag2(A0, wm * 128 + mi * 16 + lr, lc);
    if (st1) stage_half(nbuf, 1, 0, kt + 1);
    __builtin_amdgcn_s_barrier();
    __builtin_amdgcn_s_setprio(1);
    #pragma unroll
    for (int mi = 0; mi < 4; ++mi)
      #pragma unroll
      for (int ni = 0; ni < 4; ++ni)
        acc[mi][ni] = __builtin_amdgcn_mfma_f32_16x16x32_bf16(afr[mi], bfrag[ni],
                                                              acc[mi][ni], 0, 0, 0);
    __builtin_amdgcn_s_setprio(0);
    __builtin_amdgcn_s_barrier();

    // ---- ph1 ----
    #pragma unroll
    for (int mi = 0; mi < 4; ++mi) afr[mi] = frag2(A0, wm * 128 + 64 + mi * 16 + lr, lc);
    if (st1) stage_half(nbuf, 1, 1, kt + 1);
    __builtin_amdgcn_s_barrier();
    __builtin_amdgcn_s_setprio(1);
    #pragma unroll
    for (int mi = 0; mi < 4; ++mi)
      #pragma unroll
      for (int ni = 0; ni < 4; ++ni)
        acc[4 + mi][ni] = __builtin_amdgcn_mfma_f32_16x16x32_bf16(afr[mi], bfrag[ni],
                                                                  acc[4 + mi][ni], 0, 0, 0);
    __builtin_amdgcn_s_setprio(0);
    __builtin_amdgcn_s_barrier();

    // ---- ph2 ----
    #pragma unroll
    for (int ni = 0; ni < 4; ++ni) bfrag[ni] = frag2(B1, wn * 64 + ni * 16 + lr, lc);
    #pragma unroll
    for (int mi = 0; mi < 4; ++mi) afr[mi] = frag2(A1, wm * 128 + mi * 16 + lr, lc);
    if (st2) stage_half(buf, 0, 0, kt + 2);
    __builtin_amdgcn_s_barrier();
    __builtin_amdgcn_s_setprio(1);
    #pragma unroll
    for (int mi = 0; mi < 4; ++mi)
      #pragma unroll
      for (int ni = 0; ni < 4; ++ni)
        acc[mi][ni] = __builtin_amdgcn_mfma_f32_16x16x32_bf16(afr[mi], bfrag[ni],
                                                              acc[mi][ni], 0, 0, 0);
    __builtin_amdgcn_s_setprio(0);
    __builtin_amdgcn_s_barrier();

    // ---- ph3 ----
    #pragma unroll
    for (int mi = 0; mi < 4; ++mi) afr[mi] = frag2(A1, wm * 128 + 64 + mi * 16 + lr, lc);
    if (st2) {
      stage_half(buf, 0, 1, kt + 2);
      asm volatile("s_waitcnt vmcnt(4)" ::: "memory");
    } else if (st1) {
      asm volatile("s_waitcnt vmcnt(0)" ::: "memory");
    }
    __builtin_amdgcn_s_barrier();
    __builtin_amdgcn_s_setprio(1);
    #pragma unroll
    for (int mi = 0; mi < 4; ++mi)
      #pragma unroll
      for (int ni = 0; ni < 4; ++ni)
        acc[4 + mi][ni] = __builtin_amdgcn_mfma_f32_16x16x32_bf16(afr[mi], bfrag[ni],
                                                                  acc[4 + mi][ni], 0, 0, 0);
    __builtin_amdgcn_s_setprio(0);
    __builtin_amdgcn_s_barrier();
  }

  // ---- fused epilogue ----
  const int sec = n0 / DIM;           // 0=q, 1=k, 2=v (tile never straddles)
  const int h0 = (n0 % DIM) >> 7;     // first of the 2 heads in this tile

  // stage C (bf16 + bias) with swizzle scol = col ^ (s4<<4), s4 = (row>>2)&15
  {
    float bv[4];
    #pragma unroll
    for (int ni = 0; ni < 4; ++ni)
      bv[ni] = bias[n0 + wn * 64 + ni * 16 + lr];
    #pragma unroll
    for (int mi = 0; mi < 8; ++mi) {
      int rbase = wm * 128 + mi * 16 + lc * 4;
      int s4 = (mi * 4 + lc) & 15;    // == (row>>2)&15, wm*32 ≡ 0 (mod 16)
      #pragma unroll
      for (int ni = 0; ni < 4; ++ni) {
        int scol = (wn * 64 + ni * 16 + lr) ^ (s4 << 4);
        #pragma unroll
        for (int rr = 0; rr < 4; ++rr)
          lds[(rbase + rr) * 256 + scol] = f2bf(acc[mi][ni][rr] + bv[ni]);
      }
    }
  }
  __syncthreads();

  if (sec < 2) {
    // rope q/k: out[d] = x[d]*cos + sign(d) * x[d^64]*sin ; q gets scale folded
    u16* dst = sec ? Kp : Qp;
    const float sc = sec ? 1.f : (0.08838834764831845f * 1.4426950408889634f);
    #pragma unroll
    for (int i = 0; i < 16; ++i) {
      int id = i * 512 + t;
      int row = id >> 5, c16 = id & 31;
      int srow = m0 + row;
      int s4 = (row >> 2) & 15;
      int c8 = c16 * 8;
      u16x8 x  = *(const u16x8*)(lds + row * 256 + (c8 ^ (s4 << 4)));
      u16x8 xp = *(const u16x8*)(lds + row * 256 + ((c8 ^ 64) ^ (s4 << 4)));
      int h = h0 + (c8 >> 7);
      int d = c8 & 127;
      float cs[8], sn[8];
      *(float4*)(cs)     = *(const float4*)(cosb + (size_t)srow * HD + d);
      *(float4*)(cs + 4) = *(const float4*)(cosb + (size_t)srow * HD + d + 4);
      *(float4*)(sn)     = *(const float4*)(sinb + (size_t)srow * HD + d);
      *(float4*)(sn + 4) = *(const float4*)(sinb + (size_t)srow * HD + d + 4);
      const float sg = (d & 64) ? 1.f : -1.f;
      u16x8 o;
      #pragma unroll
      for (int j = 0; j < 8; ++j)
        o[j] = f2bf((bf2f(x[j]) * cs[j] + sg * bf2f(xp[j]) * sn[j]) * sc);
      *(u16x8*)(dst + ((size_t)h * S_LEN + srow) * HD + d) = o;
    }
  } else {
    // v transpose: Vt[h][d][s] <- lds[s_local][col]
    #pragma unroll
    for (int i = 0; i < 16; ++i) {
      int id = i * 512 + t;
      int col = id >> 5, sch = id & 31;
      int h = h0 + (col >> 7), d = col & 127;
      u16x8 v;
      #pragma unroll
      for (int e = 0; e < 8; ++e) {
        int row = sch * 8 + e;
        int s4 = (row >> 2) & 15;
        v[e] = lds[row * 256 + (col ^ (s4 << 4))];
      }
      *(u16x8*)(Vt + ((size_t)h * HD + d) * S_LEN + m0 + sch * 8) = v;
    }
  }
}

// ---------------- GEMM: C[M][N] = A[M][K] * B[N][K]^T (128x128, for GEMM2) ------
__device__ __forceinline__ bf16x8 lds_frag(const u16* base, int row, int ch) {
  return *(const bf16x8*)(base + row * 64 + ((ch ^ row) & 7) * 8);
}

template <bool BIAS, bool OUTF32>
__global__ __launch_bounds__(256) void gemm_bt(const u16* __restrict__ A,
                                               const u16* __restrict__ B,
                                               const float* __restrict__ bias,
                                               void* __restrict__ Cout,
                                               int M, int N, int K) {
  __shared__ u16 Asm[128 * 64];
  __shared__ u16 Bsm[128 * 64];
  const int t = threadIdx.x;
  const int l = t & 63;
  const int w = t >> 6;
  const int wm = w >> 1, wn = w & 1;
  const int m0 = blockIdx.y * 128, n0 = blockIdx.x * 128;

  f32x4 acc[4][4];
  #pragma unroll
  for (int i = 0; i < 4; ++i)
    #pragma unroll
    for (int j = 0; j < 4; ++j) acc[i][j] = f32x4{0.f, 0.f, 0.f, 0.f};

  for (int k0 = 0; k0 < K; k0 += 64) {
    __syncthreads();
    #pragma unroll
    for (int r4 = 0; r4 < 4; ++r4) {
      int C = t + r4 * 256;
      int row = C >> 3, ch = C & 7;
      int sch = (ch ^ row) & 7;
      GLL16(A + (size_t)(m0 + row) * K + k0 + sch * 8, Asm + (size_t)C * 8);
      GLL16(B + (size_t)(n0 + row) * K + k0 + sch * 8, Bsm + (size_t)C * 8);
    }
    __syncthreads();
    #pragma unroll
    for (int ks = 0; ks < 2; ++ks) {
      bf16x8 af[4], bfr[4];
      #pragma unroll
      for (int mi = 0; mi < 4; ++mi)
        af[mi] = lds_frag(Asm, wm * 64 + mi * 16 + (l & 15), ks * 4 + (l >> 4));
      #pragma unroll
      for (int ni = 0; ni < 4; ++ni)
        bfr[ni] = lds_frag(Bsm, wn * 64 + ni * 16 + (l & 15), ks * 4 + (l >> 4));
      #pragma unroll
      for (int mi = 0; mi < 4; ++mi)
        #pragma unroll
        for (int ni = 0; ni < 4; ++ni)
          acc[mi][ni] = __builtin_amdgcn_mfma_f32_16x16x32_bf16(af[mi], bfr[ni],
                                                                acc[mi][ni], 0, 0, 0);
    }
  }

  #pragma unroll
  for (int ni = 0; ni < 4; ++ni) {
    int col = n0 + wn * 64 + ni * 16 + (l & 15);
    float bv = 0.f;
    if (BIAS) bv = bias[col];
    #pragma unroll
    for (int mi = 0; mi < 4; ++mi) {
      int rbase = m0 + wm * 64 + mi * 16 + ((l >> 4) << 2);
      #pragma unroll
      for (int rr = 0; rr < 4; ++rr) {
        float v = acc[mi][ni][rr] + bv;
        if (OUTF32)
          ((float*)Cout)[(size_t)(rbase + rr) * N + col] = v;
        else
          ((u16*)Cout)[(size_t)(rbase + rr) * N + col] = f2bf(v);
      }
    }
  }
}

// -------- flash attention (R7 config): QBLK=64, 4 waves, swapped-QK^T softmax ---
__global__ __launch_bounds__(256) void attn_fwd(const u16* __restrict__ Qp,
                                                const u16* __restrict__ Kp,
                                                const u16* __restrict__ Vt,
                                                const int* __restrict__ cu,
                                                u16* __restrict__ Obf) {
  __shared__ u16 K_lds[64 * 128];    // [kv][d], chunk-swizzled
  __shared__ u16 VT_lds[128 * 64];   // [d][kv], chunk-swizzled
  __shared__ u16 P_lds[4][16 * 76];  // per-wave P[q][k], stride 76

  const int t = threadIdx.x;
  const int l = t & 63;
  const int w = t >> 6;
  const int lr = l & 15;
  const int lq = l >> 4;
  const int q0 = blockIdx.x * 64;
  const int h = blockIdx.y;

  int cs = 0, ce = S_LEN;
  #pragma unroll
  for (int b = 0; b < 4; ++b) {
    int lo = cu[b], hi = cu[b + 1];
    if (q0 >= lo && q0 < hi) { cs = lo; ce = hi; }
  }

  const int qrow = q0 + w * 16 + lr;
  bf16x8 qf[4];
  const u16* qptr = Qp + ((size_t)h * S_LEN + qrow) * HD + lq * 8;
  #pragma unroll
  for (int ks = 0; ks < 4; ++ks) qf[ks] = *(const bf16x8*)(qptr + ks * 32);

  f32x4 acc_o[8];
  #pragma unroll
  for (int i = 0; i < 8; ++i) acc_o[i] = f32x4{0.f, 0.f, 0.f, 0.f};
  float m_run = -1e30f, l_run = 0.f;   // per-lane: row q = lr

  for (int kv0 = cs; kv0 < ce; kv0 += 64) {
    __syncthreads();
    {
      const u16* kbase = Kp + ((size_t)h * S_LEN + kv0) * HD;
      #pragma unroll
      for (int r4 = 0; r4 < 4; ++r4) {
        int C = t + r4 * 256;
        int row = C >> 4, ch = C & 15;
        int sch = (ch & 8) | ((ch ^ row) & 7);
        GLL16(kbase + row * HD + sch * 8, K_lds + (size_t)C * 8);
      }
      const u16* vbase = Vt + (size_t)h * HD * S_LEN + kv0;
      #pragma unroll
      for (int r4 = 0; r4 < 4; ++r4) {
        int C = t + r4 * 256;
        int row = C >> 3, ch = C & 7;
        int sch = (ch ^ row) & 7;
        GLL16(vbase + (size_t)row * S_LEN + sch * 8, VT_lds + (size_t)C * 8);
      }
    }
    __syncthreads();

    // S^T = K Q^T : s_acc[nf] reg r holds S[q=lr][k = nf*16 + lq*4 + r]
    f32x4 s_acc[4];
    __builtin_amdgcn_s_setprio(1);
    #pragma unroll
    for (int nf = 0; nf < 4; ++nf) {
      s_acc[nf] = f32x4{0.f, 0.f, 0.f, 0.f};
      int krow = nf * 16 + lr;
      #pragma unroll
      for (int ks = 0; ks < 4; ++ks) {
        int ch = ks * 4 + lq;
        int sch = (ch & 8) | ((ch ^ krow) & 7);
        bf16x8 kf = *(const bf16x8*)(K_lds + krow * 128 + sch * 8);
        s_acc[nf] = __builtin_amdgcn_mfma_f32_16x16x32_bf16(kf, qf[ks], s_acc[nf], 0, 0, 0);
      }
    }
    __builtin_amdgcn_s_setprio(0);

    // in-register row softmax (q = lr), 16 k-values per lane
    float vmax = -1e30f;
    #pragma unroll
    for (int nf = 0; nf < 4; ++nf)
      #pragma unroll
      for (int r = 0; r < 4; ++r) vmax = fmaxf(vmax, s_acc[nf][r]);
    vmax = fmaxf(vmax, __shfl_xor(vmax, 16, 64));
    vmax = fmaxf(vmax, __shfl_xor(vmax, 32, 64));
    float mn = fmaxf(m_run, vmax);
    float alpha = __builtin_amdgcn_exp2f(m_run - mn);
    m_run = mn;
    float pv[4][4], sum = 0.f;
    #pragma unroll
    for (int nf = 0; nf < 4; ++nf)
      #pragma unroll
      for (int r = 0; r < 4; ++r) {
        float e = __builtin_amdgcn_exp2f(s_acc[nf][r] - mn);
        pv[nf][r] = e;
        sum += e;
      }
    sum += __shfl_xor(sum, 16, 64);
    sum += __shfl_xor(sum, 32, 64);
    l_run = l_run * alpha + sum;

    // rescale O: alpha for O-row q = lq*4+r lives at lane lq*16 + lq*4 + r
    float alphaO[4];
    #pragma unroll
    for (int r = 0; r < 4; ++r) alphaO[r] = __shfl(alpha, lq * 20 + r, 64);
    #pragma unroll
    for (int onf = 0; onf < 8; ++onf)
      #pragma unroll
      for (int r = 0; r < 4; ++r) acc_o[onf][r] *= alphaO[r];

    // P -> LDS: lane writes P[q=lr][k = nf*16 + lq*4 .. +3] as one b64
    u16* pl = P_lds[w];
    #pragma unroll
    for (int nf = 0; nf < 4; ++nf) {
      u16x4 pk;
      #pragma unroll
      for (int r = 0; r < 4; ++r) pk[r] = f2bf(pv[nf][r]);
      *(u16x4*)(pl + lr * 76 + nf * 16 + lq * 4) = pk;
    }

    // O += P V
    __builtin_amdgcn_s_setprio(1);
    #pragma unroll
    for (int ks = 0; ks < 2; ++ks) {
      bf16x8 pa = *(const bf16x8*)(pl + lr * 76 + ks * 32 + lq * 8);
      #pragma unroll
      for (int onf = 0; onf < 8; ++onf) {
        int d = onf * 16 + lr;
        int ch = ks * 4 + lq;
        int sch = (ch ^ d) & 7;
        bf16x8 vf = *(const bf16x8*)(VT_lds + d * 64 + sch * 8);
        acc_o[onf] = __builtin_amdgcn_mfma_f32_16x16x32_bf16(pa, vf, acc_o[onf], 0, 0, 0);
      }
    }
    __builtin_amdgcn_s_setprio(0);
  }

  // epilogue: inv for O-row q = lq*4+r fetched from lane lq*20+r
  float invO[4];
  #pragma unroll
  for (int r = 0; r < 4; ++r) invO[r] = 1.f / __shfl(l_run, lq * 20 + r, 64);
  #pragma unroll
  for (int r = 0; r < 4; ++r) {
    int srow = q0 + w * 16 + (lq << 2) + r;
    u16* orow = Obf + (size_t)srow * DIM + h * HD + lr;
    #pragma unroll
    for (int onf = 0; onf < 8; ++onf) orow[onf * 16] = f2bf(acc_o[onf][r] * invO[r]);
  }
}

extern "C" void kernel_launch(void* const* d_in, const int* in_sizes, int n_in,
                              void* d_out, int out_size, void* d_ws, size_t ws_size,
                              hipStream_t stream) {
  const float* hidden = (const float*)d_in[0];
  const float* cosb   = (const float*)d_in[1];
  const float* sinb   = (const float*)d_in[2];
  const float* qkv_w  = (const float*)d_in[3];
  const float* qkv_b  = (const float*)d_in[4];
  const float* proj_w = (const float*)d_in[5];
  const int*   cu     = (const int*)d_in[6];

  u16* Hbf   = (u16*)d_ws;                       // 4.72M u16
  u16* Wqkv  = Hbf   + (size_t)S_LEN * DIM;      // 7.08M
  u16* Wproj = Wqkv  + (size_t)QKV_N * DIM;      // 2.36M
  u16* Qp    = Wproj + (size_t)DIM * DIM;        // 4.72M (dedicated: no alias!)
  u16* Kp    = Qp    + (size_t)NH * S_LEN * HD;  // 4.72M
  u16* Vt    = Kp    + (size_t)NH * S_LEN * HD;  // 4.72M  (total ~56.6 MB)
  u16* Abf   = Hbf;   // reuse: Hbf dead after GEMM1

  cvt_bf16_3<<<2048, 256, 0, stream>>>(hidden, Hbf, S_LEN * DIM / 4,
                                       qkv_w, Wqkv, QKV_N * DIM / 4,
                                       proj_w, Wproj, DIM * DIM / 4);

  gemm_qkvf<<<(S_LEN / 256) * (QKV_N / 256), 512, 0, stream>>>(
      Hbf, Wqkv, qkv_b, cosb, sinb, Qp, Kp, Vt, S_LEN, QKV_N, DIM);

  attn_fwd<<<dim3(S_LEN / 64, NH), 256, 0, stream>>>(Qp, Kp, Vt, cu, Abf);

  gemm_bt<false, true><<<dim3(DIM / 128, S_LEN / 128), 256, 0, stream>>>(
      Abf, Wproj, nullptr, d_out, S_LEN, DIM, DIM);
}

// Round 11
// 143.228 us; speedup vs baseline: 1.2240x; 1.0537x over previous
//
#include <hip/hip_runtime.h>
#include <stdint.h>

#define S_LEN 3072
#define DIM   1536
#define NH    12
#define HD    128
#define QKV_N 4608   // 3*DIM

typedef unsigned short u16;
typedef __bf16 bf16x8 __attribute__((ext_vector_type(8)));
typedef float  f32x4  __attribute__((ext_vector_type(4)));
typedef u16    u16x8  __attribute__((ext_vector_type(8)));
typedef u16    u16x4  __attribute__((ext_vector_type(4)));

#define AS1 __attribute__((address_space(1)))
#define AS3 __attribute__((address_space(3)))
#define GLL16(g, l) __builtin_amdgcn_global_load_lds((AS1 void*)(g), (AS3 void*)(l), 16, 0, 0)

__device__ __forceinline__ u16 f2bf(float f) {
  unsigned u = __float_as_uint(f);
  u = (u + 0x7fffu + ((u >> 16) & 1u)) >> 16;   // RNE
  return (u16)u;
}
__device__ __forceinline__ float bf2f(u16 b) {
  return __uint_as_float(((unsigned)b) << 16);
}

// ---------------- fused fp32 -> bf16 convert (3 tensors, one launch) ----------
__global__ __launch_bounds__(256) void cvt_bf16_3(const float* __restrict__ in0, u16* __restrict__ out0, int n0,
                                                  const float* __restrict__ in1, u16* __restrict__ out1, int n1,
                                                  const float* __restrict__ in2, u16* __restrict__ out2, int n2) {
  int total = n0 + n1 + n2;
  int stride = gridDim.x * blockDim.x;
  for (int i = blockIdx.x * blockDim.x + threadIdx.x; i < total; i += stride) {
    const float* src; u16* dst; int j;
    if (i < n0)           { src = in0; dst = out0; j = i; }
    else if (i < n0 + n1) { src = in1; dst = out1; j = i - n0; }
    else                  { src = in2; dst = out2; j = i - n0 - n1; }
    float4 v = ((const float4*)src)[j];
    ushort4 o;
    o.x = f2bf(v.x); o.y = f2bf(v.y); o.z = f2bf(v.z); o.w = f2bf(v.w);
    ((ushort4*)dst)[j] = o;
  }
}

// ======= GEMM1 (QKV) 256x256 8-phase + FUSED epilogue: rope q/k, transpose v ===
// Main loop identical to R7 gemm_bt_256 (proven, 0 conflicts).
// Epilogue swizzle: scol = col ^ (s4<<4), s4 = (row>>3)&15.
//  - C-store: s4 const across rr (rbase%8+rr<8), 2-way max (free).
//  - rope read: u16x8 full-row coverage (optimal, swizzle-independent).
//  - V gather: s4 == sch exactly -> bank bits vary with both col and sch;
//    lane map 8 cols x 8 schs per wave => 2-way (free), global stores keep
//    128B-contiguous runs per 8-lane group.
__global__ __launch_bounds__(512, 2) void gemm_qkvf(const u16* __restrict__ A,
                                                    const u16* __restrict__ B,
                                                    const float* __restrict__ bias,
                                                    const float* __restrict__ cosb,
                                                    const float* __restrict__ sinb,
                                                    u16* __restrict__ Qp,
                                                    u16* __restrict__ Kp,
                                                    u16* __restrict__ Vt,
                                                    int M, int N, int K) {
  __shared__ __attribute__((aligned(16))) u16 lds[8 * 8192];  // 128 KiB

  const int t = threadIdx.x;
  const int l = t & 63;
  const int w = t >> 6;          // 0..7
  const int wm = w >> 2;         // 0..1  (128 rows)
  const int wn = w & 3;          // 0..3  (64 cols)
  const int lr = l & 15;
  const int lc = l >> 4;

  const int nbx = N >> 8;
  const int nwg = gridDim.x;
  const int q = nwg >> 3, r = nwg & 7;
  const int xcd = blockIdx.x & 7, rest = blockIdx.x >> 3;
  const int wgid = (xcd < r ? xcd * (q + 1) : r * (q + 1) + (xcd - r) * q) + rest;
  const int m0 = (wgid / nbx) * 256;
  const int n0 = (wgid % nbx) * 256;

  const int nk = K >> 6;

  f32x4 acc[8][4];
  #pragma unroll
  for (int i = 0; i < 8; ++i)
    #pragma unroll
    for (int j = 0; j < 4; ++j) acc[i][j] = f32x4{0.f, 0.f, 0.f, 0.f};

  auto frag2 = [&](const u16* region, int row, int ch) {
    int L = row >> 1;
    int slot = ((ch + ((row & 1) << 2)) ^ L) & 7;
    return *(const bf16x8*)(region + L * 64 + slot * 8);
  };
  auto stage_half = [&](int buf, int ks, int ab, int kt) {
    const u16* base = ab ? B : A;
    const int x0 = ab ? n0 : m0;
    u16* dst = lds + (((buf << 2) | (ks << 1) | ab) * 8192);
    #pragma unroll
    for (int i = 0; i < 2; ++i) {
      int C = t + i * 512;
      int L = C >> 3, s = C & 7;
      int u = s ^ (L & 7);
      int row = 2 * L + (u >> 2), ch = u & 3;
      const u16* src = base + (size_t)(x0 + row) * K + kt * 64 + ks * 32 + ch * 8;
      GLL16(src, dst + C * 8);
    }
  };

  stage_half(0, 0, 0, 0); stage_half(0, 0, 1, 0);
  stage_half(0, 1, 0, 0); stage_half(0, 1, 1, 0);
  if (nk > 1) { stage_half(1, 0, 0, 1); stage_half(1, 0, 1, 1); }
  asm volatile("s_waitcnt vmcnt(4)" ::: "memory");
  __builtin_amdgcn_s_barrier();

  for (int kt = 0; kt < nk; ++kt) {
    const int buf = kt & 1, nbuf = buf ^ 1;
    const bool st1 = (kt + 1 < nk);
    const bool st2 = (kt + 2 < nk);

    const u16* A0 = lds + (((buf << 2) | 0) * 8192);
    const u16* B0 = lds + (((buf << 2) | 1) * 8192);
    const u16* A1 = lds + (((buf << 2) | 2) * 8192);
    const u16* B1 = lds + (((buf << 2) | 3) * 8192);

    bf16x8 bfrag[4], afr[4];

    // ---- ph0 ----
    #pragma unroll
    for (int ni = 0; ni < 4; ++ni) bfrag[ni] = frag2(B0, wn * 64 + ni * 16 + lr, lc);
    #pragma unroll
    for (int mi = 0; mi < 4; ++mi) afr[mi] = frag2(A0, wm * 128 + mi * 16 + lr, lc);
    if (st1) stage_half(nbuf, 1, 0, kt + 1);
    __builtin_amdgcn_s_barrier();
    __builtin_amdgcn_s_setprio(1);
    #pragma unroll
    for (int mi = 0; mi < 4; ++mi)
      #pragma unroll
      for (int ni = 0; ni < 4; ++ni)
        acc[mi][ni] = __builtin_amdgcn_mfma_f32_16x16x32_bf16(afr[mi], bfrag[ni],
                                                              acc[mi][ni], 0, 0, 0);
    __builtin_amdgcn_s_setprio(0);
    __builtin_amdgcn_s_barrier();

    // ---- ph1 ----
    #pragma unroll
    for (int mi = 0; mi < 4; ++mi) afr[mi] = frag2(A0, wm * 128 + 64 + mi * 16 + lr, lc);
    if (st1) stage_half(nbuf, 1, 1, kt + 1);
    __builtin_amdgcn_s_barrier();
    __builtin_amdgcn_s_setprio(1);
    #pragma unroll
    for (int mi = 0; mi < 4; ++mi)
      #pragma unroll
      for (int ni = 0; ni < 4; ++ni)
        acc[4 + mi][ni] = __builtin_amdgcn_mfma_f32_16x16x32_bf16(afr[mi], bfrag[ni],
                                                                  acc[4 + mi][ni], 0, 0, 0);
    __builtin_amdgcn_s_setprio(0);
    __builtin_amdgcn_s_barrier();

    // ---- ph2 ----
    #pragma unroll
    for (int ni = 0; ni < 4; ++ni) bfrag[ni] = frag2(B1, wn * 64 + ni * 16 + lr, lc);
    #pragma unroll
    for (int mi = 0; mi < 4; ++mi) afr[mi] = frag2(A1, wm * 128 + mi * 16 + lr, lc);
    if (st2) stage_half(buf, 0, 0, kt + 2);
    __builtin_amdgcn_s_barrier();
    __builtin_amdgcn_s_setprio(1);
    #pragma unroll
    for (int mi = 0; mi < 4; ++mi)
      #pragma unroll
      for (int ni = 0; ni < 4; ++ni)
        acc[mi][ni] = __builtin_amdgcn_mfma_f32_16x16x32_bf16(afr[mi], bfrag[ni],
                                                              acc[mi][ni], 0, 0, 0);
    __builtin_amdgcn_s_setprio(0);
    __builtin_amdgcn_s_barrier();

    // ---- ph3 ----
    #pragma unroll
    for (int mi = 0; mi < 4; ++mi) afr[mi] = frag2(A1, wm * 128 + 64 + mi * 16 + lr, lc);
    if (st2) {
      stage_half(buf, 0, 1, kt + 2);
      asm volatile("s_waitcnt vmcnt(4)" ::: "memory");
    } else if (st1) {
      asm volatile("s_waitcnt vmcnt(0)" ::: "memory");
    }
    __builtin_amdgcn_s_barrier();
    __builtin_amdgcn_s_setprio(1);
    #pragma unroll
    for (int mi = 0; mi < 4; ++mi)
      #pragma unroll
      for (int ni = 0; ni < 4; ++ni)
        acc[4 + mi][ni] = __builtin_amdgcn_mfma_f32_16x16x32_bf16(afr[mi], bfrag[ni],
                                                                  acc[4 + mi][ni], 0, 0, 0);
    __builtin_amdgcn_s_setprio(0);
    __builtin_amdgcn_s_barrier();
  }

  // ---- fused epilogue ----
  const int sec = n0 / DIM;           // 0=q, 1=k, 2=v (tile never straddles)
  const int h0 = (n0 % DIM) >> 7;     // first of the 2 heads in this tile

  // stage C (bf16 + bias), swizzle scol = col ^ (s4<<4), s4 = (row>>3)&15
  {
    float bv[4];
    #pragma unroll
    for (int ni = 0; ni < 4; ++ni)
      bv[ni] = bias[n0 + wn * 64 + ni * 16 + lr];
    #pragma unroll
    for (int mi = 0; mi < 8; ++mi) {
      int rbase = wm * 128 + mi * 16 + lc * 4;
      int s4 = (rbase >> 3) & 15;     // rr<4 never carries into bit 3
      #pragma unroll
      for (int ni = 0; ni < 4; ++ni) {
        int scol = (wn * 64 + ni * 16 + lr) ^ (s4 << 4);
        #pragma unroll
        for (int rr = 0; rr < 4; ++rr)
          lds[(rbase + rr) * 256 + scol] = f2bf(acc[mi][ni][rr] + bv[ni]);
      }
    }
  }
  __syncthreads();

  if (sec < 2) {
    // rope q/k: out[d] = x[d]*cos + sign(d) * x[d^64]*sin ; q gets scale folded
    u16* dst = sec ? Kp : Qp;
    const float sc = sec ? 1.f : (0.08838834764831845f * 1.4426950408889634f);
    #pragma unroll
    for (int i = 0; i < 16; ++i) {
      int id = i * 512 + t;
      int row = id >> 5, c16 = id & 31;
      int srow = m0 + row;
      int s4 = (row >> 3) & 15;
      int c8 = c16 * 8;
      u16x8 x  = *(const u16x8*)(lds + row * 256 + (c8 ^ (s4 << 4)));
      u16x8 xp = *(const u16x8*)(lds + row * 256 + ((c8 ^ 64) ^ (s4 << 4)));
      int h = h0 + (c8 >> 7);
      int d = c8 & 127;
      float cs[8], sn[8];
      *(float4*)(cs)     = *(const float4*)(cosb + (size_t)srow * HD + d);
      *(float4*)(cs + 4) = *(const float4*)(cosb + (size_t)srow * HD + d + 4);
      *(float4*)(sn)     = *(const float4*)(sinb + (size_t)srow * HD + d);
      *(float4*)(sn + 4) = *(const float4*)(sinb + (size_t)srow * HD + d + 4);
      const float sg = (d & 64) ? 1.f : -1.f;
      u16x8 o;
      #pragma unroll
      for (int j = 0; j < 8; ++j)
        o[j] = f2bf((bf2f(x[j]) * cs[j] + sg * bf2f(xp[j]) * sn[j]) * sc);
      *(u16x8*)(dst + ((size_t)h * S_LEN + srow) * HD + d) = o;
    }
  } else {
    // v transpose: Vt[h][d][s] <- lds[s_local][col].
    // lane map: col = oct*8 + (l>>3)&7, sch = (l&7) | schhi -> s4 = sch
    // gives bank bits from both col and sch => 2-way; global stores stay
    // 128B-contiguous per 8-lane group.
    #pragma unroll
    for (int i = 0; i < 16; ++i) {
      int id = i * 512 + t;
      int col = (((id >> 6) & 31) << 3) | ((id >> 3) & 7);
      int sch = (id & 7) | (((id >> 11) & 3) << 3);
      int h = h0 + (col >> 7), d = col & 127;
      int scol = col ^ ((sch & 15) << 4);   // s4 = (row>>3)&15 = sch
      u16x8 v;
      #pragma unroll
      for (int e = 0; e < 8; ++e)
        v[e] = lds[(sch * 8 + e) * 256 + scol];
      *(u16x8*)(Vt + ((size_t)h * HD + d) * S_LEN + m0 + sch * 8) = v;
    }
  }
}

// ---------------- GEMM: C[M][N] = A[M][K] * B[N][K]^T (128x128, for GEMM2) ------
__device__ __forceinline__ bf16x8 lds_frag(const u16* base, int row, int ch) {
  return *(const bf16x8*)(base + row * 64 + ((ch ^ row) & 7) * 8);
}

template <bool BIAS, bool OUTF32>
__global__ __launch_bounds__(256) void gemm_bt(const u16* __restrict__ A,
                                               const u16* __restrict__ B,
                                               const float* __restrict__ bias,
                                               void* __restrict__ Cout,
                                               int M, int N, int K) {
  __shared__ u16 Asm[128 * 64];
  __shared__ u16 Bsm[128 * 64];
  const int t = threadIdx.x;
  const int l = t & 63;
  const int w = t >> 6;
  const int wm = w >> 1, wn = w & 1;
  const int m0 = blockIdx.y * 128, n0 = blockIdx.x * 128;

  f32x4 acc[4][4];
  #pragma unroll
  for (int i = 0; i < 4; ++i)
    #pragma unroll
    for (int j = 0; j < 4; ++j) acc[i][j] = f32x4{0.f, 0.f, 0.f, 0.f};

  for (int k0 = 0; k0 < K; k0 += 64) {
    __syncthreads();
    #pragma unroll
    for (int r4 = 0; r4 < 4; ++r4) {
      int C = t + r4 * 256;
      int row = C >> 3, ch = C & 7;
      int sch = (ch ^ row) & 7;
      GLL16(A + (size_t)(m0 + row) * K + k0 + sch * 8, Asm + (size_t)C * 8);
      GLL16(B + (size_t)(n0 + row) * K + k0 + sch * 8, Bsm + (size_t)C * 8);
    }
    __syncthreads();
    #pragma unroll
    for (int ks = 0; ks < 2; ++ks) {
      bf16x8 af[4], bfr[4];
      #pragma unroll
      for (int mi = 0; mi < 4; ++mi)
        af[mi] = lds_frag(Asm, wm * 64 + mi * 16 + (l & 15), ks * 4 + (l >> 4));
      #pragma unroll
      for (int ni = 0; ni < 4; ++ni)
        bfr[ni] = lds_frag(Bsm, wn * 64 + ni * 16 + (l & 15), ks * 4 + (l >> 4));
      #pragma unroll
      for (int mi = 0; mi < 4; ++mi)
        #pragma unroll
        for (int ni = 0; ni < 4; ++ni)
          acc[mi][ni] = __builtin_amdgcn_mfma_f32_16x16x32_bf16(af[mi], bfr[ni],
                                                                acc[mi][ni], 0, 0, 0);
    }
  }

  #pragma unroll
  for (int ni = 0; ni < 4; ++ni) {
    int col = n0 + wn * 64 + ni * 16 + (l & 15);
    float bv = 0.f;
    if (BIAS) bv = bias[col];
    #pragma unroll
    for (int mi = 0; mi < 4; ++mi) {
      int rbase = m0 + wm * 64 + mi * 16 + ((l >> 4) << 2);
      #pragma unroll
      for (int rr = 0; rr < 4; ++rr) {
        float v = acc[mi][ni][rr] + bv;
        if (OUTF32)
          ((float*)Cout)[(size_t)(rbase + rr) * N + col] = v;
        else
          ((u16*)Cout)[(size_t)(rbase + rr) * N + col] = f2bf(v);
      }
    }
  }
}

// -------- flash attention (R7 config): QBLK=64, 4 waves, swapped-QK^T softmax ---
__global__ __launch_bounds__(256) void attn_fwd(const u16* __restrict__ Qp,
                                                const u16* __restrict__ Kp,
                                                const u16* __restrict__ Vt,
                                                const int* __restrict__ cu,
                                                u16* __restrict__ Obf) {
  __shared__ u16 K_lds[64 * 128];    // [kv][d], chunk-swizzled
  __shared__ u16 VT_lds[128 * 64];   // [d][kv], chunk-swizzled
  __shared__ u16 P_lds[4][16 * 76];  // per-wave P[q][k], stride 76

  const int t = threadIdx.x;
  const int l = t & 63;
  const int w = t >> 6;
  const int lr = l & 15;
  const int lq = l >> 4;
  const int q0 = blockIdx.x * 64;
  const int h = blockIdx.y;

  int cs = 0, ce = S_LEN;
  #pragma unroll
  for (int b = 0; b < 4; ++b) {
    int lo = cu[b], hi = cu[b + 1];
    if (q0 >= lo && q0 < hi) { cs = lo; ce = hi; }
  }

  const int qrow = q0 + w * 16 + lr;
  bf16x8 qf[4];
  const u16* qptr = Qp + ((size_t)h * S_LEN + qrow) * HD + lq * 8;
  #pragma unroll
  for (int ks = 0; ks < 4; ++ks) qf[ks] = *(const bf16x8*)(qptr + ks * 32);

  f32x4 acc_o[8];
  #pragma unroll
  for (int i = 0; i < 8; ++i) acc_o[i] = f32x4{0.f, 0.f, 0.f, 0.f};
  float m_run = -1e30f, l_run = 0.f;   // per-lane: row q = lr

  for (int kv0 = cs; kv0 < ce; kv0 += 64) {
    __syncthreads();
    {
      const u16* kbase = Kp + ((size_t)h * S_LEN + kv0) * HD;
      #pragma unroll
      for (int r4 = 0; r4 < 4; ++r4) {
        int C = t + r4 * 256;
        int row = C >> 4, ch = C & 15;
        int sch = (ch & 8) | ((ch ^ row) & 7);
        GLL16(kbase + row * HD + sch * 8, K_lds + (size_t)C * 8);
      }
      const u16* vbase = Vt + (size_t)h * HD * S_LEN + kv0;
      #pragma unroll
      for (int r4 = 0; r4 < 4; ++r4) {
        int C = t + r4 * 256;
        int row = C >> 3, ch = C & 7;
        int sch = (ch ^ row) & 7;
        GLL16(vbase + (size_t)row * S_LEN + sch * 8, VT_lds + (size_t)C * 8);
      }
    }
    __syncthreads();

    // S^T = K Q^T : s_acc[nf] reg r holds S[q=lr][k = nf*16 + lq*4 + r]
    f32x4 s_acc[4];
    __builtin_amdgcn_s_setprio(1);
    #pragma unroll
    for (int nf = 0; nf < 4; ++nf) {
      s_acc[nf] = f32x4{0.f, 0.f, 0.f, 0.f};
      int krow = nf * 16 + lr;
      #pragma unroll
      for (int ks = 0; ks < 4; ++ks) {
        int ch = ks * 4 + lq;
        int sch = (ch & 8) | ((ch ^ krow) & 7);
        bf16x8 kf = *(const bf16x8*)(K_lds + krow * 128 + sch * 8);
        s_acc[nf] = __builtin_amdgcn_mfma_f32_16x16x32_bf16(kf, qf[ks], s_acc[nf], 0, 0, 0);
      }
    }
    __builtin_amdgcn_s_setprio(0);

    // in-register row softmax (q = lr), 16 k-values per lane
    float vmax = -1e30f;
    #pragma unroll
    for (int nf = 0; nf < 4; ++nf)
      #pragma unroll
      for (int r = 0; r < 4; ++r) vmax = fmaxf(vmax, s_acc[nf][r]);
    vmax = fmaxf(vmax, __shfl_xor(vmax, 16, 64));
    vmax = fmaxf(vmax, __shfl_xor(vmax, 32, 64));
    float mn = fmaxf(m_run, vmax);
    float alpha = __builtin_amdgcn_exp2f(m_run - mn);
    m_run = mn;
    float pv[4][4], sum = 0.f;
    #pragma unroll
    for (int nf = 0; nf < 4; ++nf)
      #pragma unroll
      for (int r = 0; r < 4; ++r) {
        float e = __builtin_amdgcn_exp2f(s_acc[nf][r] - mn);
        pv[nf][r] = e;
        sum += e;
      }
    sum += __shfl_xor(sum, 16, 64);
    sum += __shfl_xor(sum, 32, 64);
    l_run = l_run * alpha + sum;

    // rescale O: alpha for O-row q = lq*4+r lives at lane lq*16 + lq*4 + r
    float alphaO[4];
    #pragma unroll
    for (int r = 0; r < 4; ++r) alphaO[r] = __shfl(alpha, lq * 20 + r, 64);
    #pragma unroll
    for (int onf = 0; onf < 8; ++onf)
      #pragma unroll
      for (int r = 0; r < 4; ++r) acc_o[onf][r] *= alphaO[r];

    // P -> LDS: lane writes P[q=lr][k = nf*16 + lq*4 .. +3] as one b64
    u16* pl = P_lds[w];
    #pragma unroll
    for (int nf = 0; nf < 4; ++nf) {
      u16x4 pk;
      #pragma unroll
      for (int r = 0; r < 4; ++r) pk[r] = f2bf(pv[nf][r]);
      *(u16x4*)(pl + lr * 76 + nf * 16 + lq * 4) = pk;
    }

    // O += P V
    __builtin_amdgcn_s_setprio(1);
    #pragma unroll
    for (int ks = 0; ks < 2; ++ks) {
      bf16x8 pa = *(const bf16x8*)(pl + lr * 76 + ks * 32 + lq * 8);
      #pragma unroll
      for (int onf = 0; onf < 8; ++onf) {
        int d = onf * 16 + lr;
        int ch = ks * 4 + lq;
        int sch = (ch ^ d) & 7;
        bf16x8 vf = *(const bf16x8*)(VT_lds + d * 64 + sch * 8);
        acc_o[onf] = __builtin_amdgcn_mfma_f32_16x16x32_bf16(pa, vf, acc_o[onf], 0, 0, 0);
      }
    }
    __builtin_amdgcn_s_setprio(0);
  }

  // epilogue: inv for O-row q = lq*4+r fetched from lane lq*20+r
  float invO[4];
  #pragma unroll
  for (int r = 0; r < 4; ++r) invO[r] = 1.f / __shfl(l_run, lq * 20 + r, 64);
  #pragma unroll
  for (int r = 0; r < 4; ++r) {
    int srow = q0 + w * 16 + (lq << 2) + r;
    u16* orow = Obf + (size_t)srow * DIM + h * HD + lr;
    #pragma unroll
    for (int onf = 0; onf < 8; ++onf) orow[onf * 16] = f2bf(acc_o[onf][r] * invO[r]);
  }
}

extern "C" void kernel_launch(void* const* d_in, const int* in_sizes, int n_in,
                              void* d_out, int out_size, void* d_ws, size_t ws_size,
                              hipStream_t stream) {
  const float* hidden = (const float*)d_in[0];
  const float* cosb   = (const float*)d_in[1];
  const float* sinb   = (const float*)d_in[2];
  const float* qkv_w  = (const float*)d_in[3];
  const float* qkv_b  = (const float*)d_in[4];
  const float* proj_w = (const float*)d_in[5];
  const int*   cu     = (const int*)d_in[6];

  u16* Hbf   = (u16*)d_ws;                       // 4.72M u16
  u16* Wqkv  = Hbf   + (size_t)S_LEN * DIM;      // 7.08M
  u16* Wproj = Wqkv  + (size_t)QKV_N * DIM;      // 2.36M
  u16* Qp    = Wproj + (size_t)DIM * DIM;        // 4.72M (dedicated: no alias!)
  u16* Kp    = Qp    + (size_t)NH * S_LEN * HD;  // 4.72M
  u16* Vt    = Kp    + (size_t)NH * S_LEN * HD;  // 4.72M  (total ~56.6 MB)
  u16* Abf   = Hbf;   // reuse: Hbf dead after GEMM1

  cvt_bf16_3<<<2048, 256, 0, stream>>>(hidden, Hbf, S_LEN * DIM / 4,
                                       qkv_w, Wqkv, QKV_N * DIM / 4,
                                       proj_w, Wproj, DIM * DIM / 4);

  gemm_qkvf<<<(S_LEN / 256) * (QKV_N / 256), 512, 0, stream>>>(
      Hbf, Wqkv, qkv_b, cosb, sinb, Qp, Kp, Vt, S_LEN, QKV_N, DIM);

  attn_fwd<<<dim3(S_LEN / 64, NH), 256, 0, stream>>>(Qp, Kp, Vt, cu, Abf);

  gemm_bt<false, true><<<dim3(DIM / 128, S_LEN / 128), 256, 0, stream>>>(
      Abf, Wproj, nullptr, d_out, S_LEN, DIM, DIM);
}